// Round 1
// baseline (167.967 us; speedup 1.0000x reference)
//
#include <hip/hip_runtime.h>
#include <math.h>

#define B 8
#define H 384
#define W 384
#define HW (H*W)
#define NTOT (B*HW)
#define INF_D 1.0e4f

// ws layout:
//   [0..255]          double acc[32]: 0=bce_sum, 1..8=sum_p[b], 9..16=sum_pt[b],
//                                     17..24=sum_t[b], 25=loss2 dot
//   [512 ..)          float fpos[NTOT]   (squared vertical dist to nearest pos)
//   [512+4*NTOT ..)   float fneg[NTOT]   (squared vertical dist to nearest neg)
//   [512+8*NTOT ..)   float sumA[HW]     (sum over b of |p - t|)

// ---------------- kernel 1: BCE + dice partial sums ----------------
// grid = 8 batches * 36 chunks, 256 thr, 16 elems/thr (36*256*16 = 147456 = HW)
__global__ __launch_bounds__(256) void k_bce_dice(const float* __restrict__ pred,
                                                  const int* __restrict__ tgt,
                                                  double* __restrict__ acc) {
    int b = blockIdx.x / 36;
    int chunk = blockIdx.x % 36;
    int base = b * HW + chunk * 4096 + threadIdx.x;
    float s_bce = 0.f, s_p = 0.f, s_pt = 0.f;
    int s_t = 0;
#pragma unroll
    for (int e = 0; e < 16; ++e) {
        int idx = base + e * 256;
        float x = pred[idx];
        int t = tgt[idx];
        float sp = fmaxf(x, 0.f) + log1pf(expf(-fabsf(x)));   // softplus(x)
        float p = 1.f / (1.f + expf(-x));
        s_bce += sp - x * (float)t;
        s_p += p;
        if (t) { s_pt += p; s_t++; }
    }
    double v0 = s_bce, v1 = s_p, v2 = s_pt, v3 = (double)s_t;
#pragma unroll
    for (int o = 32; o; o >>= 1) {
        v0 += __shfl_down(v0, o);
        v1 += __shfl_down(v1, o);
        v2 += __shfl_down(v2, o);
        v3 += __shfl_down(v3, o);
    }
    __shared__ double lds[4][4];
    int wave = threadIdx.x >> 6, lane = threadIdx.x & 63;
    if (lane == 0) { lds[wave][0] = v0; lds[wave][1] = v1; lds[wave][2] = v2; lds[wave][3] = v3; }
    __syncthreads();
    if (threadIdx.x == 0) {
        double a0 = 0, a1 = 0, a2 = 0, a3 = 0;
        for (int wv = 0; wv < 4; ++wv) { a0 += lds[wv][0]; a1 += lds[wv][1]; a2 += lds[wv][2]; a3 += lds[wv][3]; }
        atomicAdd(&acc[0], a0);
        atomicAdd(&acc[1 + b], a1);
        atomicAdd(&acc[9 + b], a2);
        atomicAdd(&acc[17 + b], a3);
    }
}

// ---------------- kernel 2: sumA[pix] = sum_b |sigmoid(pred)-t| ----------------
__global__ __launch_bounds__(256) void k_sumA(const float* __restrict__ pred,
                                              const int* __restrict__ tgt,
                                              float* __restrict__ sumA) {
    int pix = blockIdx.x * 256 + threadIdx.x;
    float s = 0.f;
#pragma unroll
    for (int b = 0; b < B; ++b) {
        float x = pred[b * HW + pix];
        int t = tgt[b * HW + pix];
        float p = 1.f / (1.f + expf(-x));
        s += t ? (1.f - p) : p;
    }
    sumA[pix] = s;
}

// ---------------- kernel 3: vertical 1-D distance (both masks), writes d^2 ----------------
// one thread per (b,w) column: 8*384 = 3072 threads
__global__ __launch_bounds__(256) void k_vert(const int* __restrict__ tgt,
                                              float* __restrict__ fp,
                                              float* __restrict__ fn) {
    int g = blockIdx.x * 256 + threadIdx.x;      // 0..3071
    int b = g / W, w = g % W;
    const int* tcol = tgt + b * HW + w;
    float* fpc = fp + b * HW + w;
    float* fnc = fn + b * HW + w;
    float cp = INF_D, cn = INF_D;
    for (int h = 0; h < H; ++h) {
        int t = tcol[h * W];
        cp = t ? 0.f : fminf(cp + 1.f, INF_D);   // dist to nearest pos (zero of negmask)
        cn = t ? fminf(cn + 1.f, INF_D) : 0.f;   // dist to nearest neg
        fpc[h * W] = cp;
        fnc[h * W] = cn;
    }
    cp = INF_D; cn = INF_D;
    for (int h = H - 1; h >= 0; --h) {
        int t = tcol[h * W];
        cp = t ? 0.f : fminf(cp + 1.f, INF_D);
        cn = t ? fminf(cn + 1.f, INF_D) : 0.f;
        float dp = fminf(fpc[h * W], cp);
        float dn = fminf(fnc[h * W], cn);
        fpc[h * W] = dp * dp;
        fnc[h * W] = dn * dn;
    }
}

// ---------------- kernel 4: row lower-envelope + loss2 dot ----------------
// one block (64 thr) per (b,h) row: 3072 blocks. 6 output cols per thread.
__global__ __launch_bounds__(64) void k_row(const float* __restrict__ fp,
                                            const float* __restrict__ fn,
                                            const float* __restrict__ sumA,
                                            double* __restrict__ acc) {
    int bh = blockIdx.x;
    int b = bh / H, h = bh % H;
    __shared__ float lfp[W], lfn[W];
    const float* rowp = fp + b * HW + h * W;
    const float* rown = fn + b * HW + h * W;
    for (int j = threadIdx.x; j < W; j += 64) { lfp[j] = rowp[j]; lfn[j] = rown[j]; }
    __syncthreads();

    float Dp[6], Dn[6];
#pragma unroll
    for (int k = 0; k < 6; ++k) { Dp[k] = 3.0e38f; Dn[k] = 3.0e38f; }
    float d0 = (float)threadIdx.x;
#pragma unroll 4
    for (int j = 0; j < W; ++j) {
        float fpv = lfp[j], fnv = lfn[j];
        float d = d0 - (float)j;
#pragma unroll
        for (int k = 0; k < 6; ++k) {
            float dd = d + (float)(k * 64);
            Dp[k] = fminf(Dp[k], fmaf(dd, dd, fpv));   // (i-j)^2 exact (<2^24), same as ref
            Dn[k] = fminf(Dn[k], fmaf(dd, dd, fnv));
        }
    }
    float partial = 0.f;
#pragma unroll
    for (int k = 0; k < 6; ++k) {
        float s = fabsf(sqrtf(Dp[k]) - sqrtf(Dn[k]));          // |sdf| at (b,h,i)
        partial += s * sumA[h * W + threadIdx.x + k * 64];
    }
    double v = partial;
#pragma unroll
    for (int o = 32; o; o >>= 1) v += __shfl_down(v, o);
    if (threadIdx.x == 0) atomicAdd(&acc[25], v);
}

// ---------------- kernel 5: combine ----------------
__global__ void k_final(const double* __restrict__ acc, float* __restrict__ out) {
    if (threadIdx.x == 0 && blockIdx.x == 0) {
        double bce = acc[0] / (double)NTOT;
        double dsum = 0.0;
        for (int b = 0; b < B; ++b) {
            double sp = acc[1 + b], spt = acc[9 + b], st = acc[17 + b];
            dsum += (2.0 * spt + 1e-5) / (sp + st + 1e-5);
        }
        double dice = dsum / (double)B;
        double loss1 = 0.5 * bce + (1.0 - dice);
        double loss2 = acc[25] / ((double)B * (double)B * (double)HW);
        out[0] = (float)(0.7 * loss1 + 0.03 * loss2);
    }
}

extern "C" void kernel_launch(void* const* d_in, const int* in_sizes, int n_in,
                              void* d_out, int out_size, void* d_ws, size_t ws_size,
                              hipStream_t stream) {
    const float* pred = (const float*)d_in[0];
    const int* tgt = (const int*)d_in[1];
    float* out = (float*)d_out;
    char* ws = (char*)d_ws;
    double* acc = (double*)ws;
    float* fp = (float*)(ws + 512);
    float* fn = fp + NTOT;
    float* sumA = fn + NTOT;

    hipMemsetAsync(ws, 0, 512, stream);
    k_bce_dice<<<8 * 36, 256, 0, stream>>>(pred, tgt, acc);
    k_sumA<<<HW / 256, 256, 0, stream>>>(pred, tgt, sumA);
    k_vert<<<(B * W) / 256, 256, 0, stream>>>(tgt, fp, fn);
    k_row<<<B * H, 64, 0, stream>>>(fp, fn, sumA, acc);
    k_final<<<1, 1, 0, stream>>>(acc, out);
}

// Round 2
// 140.700 us; speedup vs baseline: 1.1938x; 1.1938x over previous
//
#include <hip/hip_runtime.h>
#include <math.h>

#define B 8
#define H 384
#define W 384
#define HW (H*W)
#define NTOT (B*HW)
#define INF_D 1.0e4f

// ws layout:
//   [0..255]        double acc[32]: 0=bce_sum, 1..8=sum_p[b], 9..16=sum_pt[b],
//                                   17..24=sum_t[b], 25=loss2 dot
//   [512 ..)        float2 g2[NTOT]  (x: fpos+w^2, y: fneg+w^2 after k_vert)
//   [512+8*NTOT ..) float sumA[HW]   (sum over b of |p - t|)

// ---------------- kernel 1: BCE + dice partial sums ----------------
__global__ __launch_bounds__(256) void k_bce_dice(const float* __restrict__ pred,
                                                  const int* __restrict__ tgt,
                                                  double* __restrict__ acc) {
    int b = blockIdx.x / 36;
    int chunk = blockIdx.x % 36;
    int base = b * HW + chunk * 4096 + threadIdx.x;
    float s_bce = 0.f, s_p = 0.f, s_pt = 0.f;
    int s_t = 0;
#pragma unroll
    for (int e = 0; e < 16; ++e) {
        int idx = base + e * 256;
        float x = pred[idx];
        int t = tgt[idx];
        float sp = fmaxf(x, 0.f) + log1pf(expf(-fabsf(x)));   // softplus(x)
        float p = 1.f / (1.f + expf(-x));
        s_bce += sp - x * (float)t;
        s_p += p;
        if (t) { s_pt += p; s_t++; }
    }
    double v0 = s_bce, v1 = s_p, v2 = s_pt, v3 = (double)s_t;
#pragma unroll
    for (int o = 32; o; o >>= 1) {
        v0 += __shfl_down(v0, o);
        v1 += __shfl_down(v1, o);
        v2 += __shfl_down(v2, o);
        v3 += __shfl_down(v3, o);
    }
    __shared__ double lds[4][4];
    int wave = threadIdx.x >> 6, lane = threadIdx.x & 63;
    if (lane == 0) { lds[wave][0] = v0; lds[wave][1] = v1; lds[wave][2] = v2; lds[wave][3] = v3; }
    __syncthreads();
    if (threadIdx.x == 0) {
        double a0 = 0, a1 = 0, a2 = 0, a3 = 0;
        for (int wv = 0; wv < 4; ++wv) { a0 += lds[wv][0]; a1 += lds[wv][1]; a2 += lds[wv][2]; a3 += lds[wv][3]; }
        atomicAdd(&acc[0], a0);
        atomicAdd(&acc[1 + b], a1);
        atomicAdd(&acc[9 + b], a2);
        atomicAdd(&acc[17 + b], a3);
    }
}

// ---------------- kernel 2: sumA[pix] = sum_b |sigmoid(pred)-t| ----------------
__global__ __launch_bounds__(256) void k_sumA(const float* __restrict__ pred,
                                              const int* __restrict__ tgt,
                                              float* __restrict__ sumA) {
    int pix = blockIdx.x * 256 + threadIdx.x;
    float s = 0.f;
#pragma unroll
    for (int b = 0; b < B; ++b) {
        float x = pred[b * HW + pix];
        int t = tgt[b * HW + pix];
        float p = 1.f / (1.f + expf(-x));
        s += t ? (1.f - p) : p;
    }
    sumA[pix] = s;
}

// ---------------- kernel 3: vertical 1-D distance, register/LDS scan ----------------
// 48 blocks x 64 thr; thread = column (b,w). Bitmask in LDS, scans in registers.
// Output: g2[b,h,w] = (dpos^2 + w^2, dneg^2 + w^2)
__global__ __launch_bounds__(64) void k_vert(const int* __restrict__ tgt,
                                             float2* __restrict__ g2) {
    __shared__ unsigned bm[12][64];
    int tid = threadIdx.x;
    int b = blockIdx.x / 6;
    int w = (blockIdx.x % 6) * 64 + tid;
    const int* tcol = tgt + b * HW + w;
    float2* gcol = g2 + b * HW + w;

    // pack 384 column bits into 12 words (coalesced, independent loads)
    for (int wd = 0; wd < 12; ++wd) {
        const int* p = tcol + wd * 32 * W;
        unsigned m = 0;
#pragma unroll
        for (int i = 0; i < 32; ++i)
            m |= (p[i * W] != 0 ? (1u << i) : 0u);
        bm[wd][tid] = m;   // own slot only — no barrier needed
    }

    // forward scan: store raw (cp, cn)
    float cp = INF_D, cn = INF_D;
    {
        float2* gc = gcol;
        for (int wd = 0; wd < 12; ++wd) {
            unsigned m = bm[wd][tid];
#pragma unroll
            for (int i = 0; i < 32; ++i) {
                bool t = (m >> i) & 1u;
                cp = t ? 0.f : fminf(cp + 1.f, INF_D);
                cn = t ? fminf(cn + 1.f, INF_D) : 0.f;
                *gc = make_float2(cp, cn);
                gc += W;
            }
        }
    }

    // backward scan + combine + square + add w^2
    float ww = (float)(w * w);
    cp = INF_D; cn = INF_D;
    {
        float2* gc = gcol + (H - 1) * W;
        for (int wd = 11; wd >= 0; --wd) {
            unsigned m = bm[wd][tid];
#pragma unroll
            for (int i = 31; i >= 0; --i) {
                bool t = (m >> i) & 1u;
                cp = t ? 0.f : fminf(cp + 1.f, INF_D);
                cn = t ? fminf(cn + 1.f, INF_D) : 0.f;
                float2 f = *gc;
                float dp = fminf(f.x, cp);
                float dn = fminf(f.y, cn);
                *gc = make_float2(fmaf(dp, dp, ww), fmaf(dn, dn, ww));
                gc -= W;
            }
        }
    }
}

// ---------------- kernel 4: row lower-envelope + loss2 dot ----------------
// D[i] = min_j f[j]+(i-j)^2 = i^2 + min_j (g[j] - 2ij),  g[j] = f[j]+j^2 (from k_vert)
__global__ __launch_bounds__(64) void k_row(const float2* __restrict__ g2,
                                            const float* __restrict__ sumA,
                                            double* __restrict__ acc) {
    int bh = blockIdx.x;
    int b = bh / H, h = bh % H;
    __shared__ float4 lgbuf[W / 2];
    const float2* row = g2 + b * HW + h * W;
    float2* lg2 = (float2*)lgbuf;
    for (int j = threadIdx.x; j < W; j += 64) lg2[j] = row[j];
    __syncthreads();

    float Dp[6], Dn[6], m2i[6];
#pragma unroll
    for (int k = 0; k < 6; ++k) {
        Dp[k] = 3.0e38f; Dn[k] = 3.0e38f;
        m2i[k] = -2.0f * (float)(threadIdx.x + 64 * k);
    }
#pragma unroll 4
    for (int jj = 0; jj < W / 2; ++jj) {
        float4 g = lgbuf[jj];                 // (gp[2jj], gn[2jj], gp[2jj+1], gn[2jj+1])
        float j0 = (float)(2 * jj), j1 = (float)(2 * jj + 1);
#pragma unroll
        for (int k = 0; k < 6; ++k) {
            Dp[k] = fminf(fminf(fmaf(m2i[k], j0, g.x), fmaf(m2i[k], j1, g.z)), Dp[k]);
            Dn[k] = fminf(fminf(fmaf(m2i[k], j0, g.y), fmaf(m2i[k], j1, g.w)), Dn[k]);
        }
    }
    float partial = 0.f;
#pragma unroll
    for (int k = 0; k < 6; ++k) {
        int i = threadIdx.x + 64 * k;
        float fi = (float)i;
        float ii = fi * fi;
        float s = fabsf(sqrtf(Dp[k] + ii) - sqrtf(Dn[k] + ii));   // |sdf| at (b,h,i)
        partial += s * sumA[h * W + i];
    }
    double v = partial;
#pragma unroll
    for (int o = 32; o; o >>= 1) v += __shfl_down(v, o);
    if (threadIdx.x == 0) atomicAdd(&acc[25], v);
}

// ---------------- kernel 5: combine ----------------
__global__ void k_final(const double* __restrict__ acc, float* __restrict__ out) {
    if (threadIdx.x == 0 && blockIdx.x == 0) {
        double bce = acc[0] / (double)NTOT;
        double dsum = 0.0;
        for (int b = 0; b < B; ++b) {
            double sp = acc[1 + b], spt = acc[9 + b], st = acc[17 + b];
            dsum += (2.0 * spt + 1e-5) / (sp + st + 1e-5);
        }
        double dice = dsum / (double)B;
        double loss1 = 0.5 * bce + (1.0 - dice);
        double loss2 = acc[25] / ((double)B * (double)B * (double)HW);
        out[0] = (float)(0.7 * loss1 + 0.03 * loss2);
    }
}

extern "C" void kernel_launch(void* const* d_in, const int* in_sizes, int n_in,
                              void* d_out, int out_size, void* d_ws, size_t ws_size,
                              hipStream_t stream) {
    const float* pred = (const float*)d_in[0];
    const int* tgt = (const int*)d_in[1];
    float* out = (float*)d_out;
    char* ws = (char*)d_ws;
    double* acc = (double*)ws;
    float2* g2 = (float2*)(ws + 512);
    float* sumA = (float*)(ws + 512 + 8 * (size_t)NTOT);

    hipMemsetAsync(ws, 0, 512, stream);
    k_bce_dice<<<8 * 36, 256, 0, stream>>>(pred, tgt, acc);
    k_sumA<<<HW / 256, 256, 0, stream>>>(pred, tgt, sumA);
    k_vert<<<B * 6, 64, 0, stream>>>(tgt, g2);
    k_row<<<B * H, 64, 0, stream>>>(g2, sumA, acc);
    k_final<<<1, 1, 0, stream>>>(acc, out);
}

// Round 3
// 53.786 us; speedup vs baseline: 3.1229x; 2.6159x over previous
//
#include <hip/hip_runtime.h>
#include <math.h>

#define B 8
#define H 384
#define W 384
#define HW (H*W)
#define NTOT (B*HW)
#define INF_I 10000

// ws layout (bytes):
//   part2 @ 0        : 576*25 doubles  (k_fused per-block partials)   115200 B
//   part  @ 115200   : 3072 doubles    (k_row per-block partials)      24576 B
//   g2u   @ 139776   : NTOT uint       (dpos | dneg<<16, vertical)   4718592 B
//   sumA  @ 4858368  : HW float        (sum_b |p - t|)                589824 B

// ---------------- kernel 1: fused BCE + dice partials + sumA ----------------
// thread = pixel, loops over 8 batches. No atomics: per-block partials to ws.
__global__ __launch_bounds__(256) void k_fused(const float* __restrict__ pred,
                                               const int* __restrict__ tgt,
                                               float* __restrict__ sumA,
                                               double* __restrict__ part2) {
    int pix = blockIdx.x * 256 + threadIdx.x;
    float vals[25];                       // 0=bce, 1+b=p, 9+b=p*t, 17+b=t
    float sA = 0.f, bce = 0.f;
#pragma unroll
    for (int b = 0; b < 8; ++b) {
        float x = pred[b * HW + pix];
        int t = tgt[b * HW + pix];
        float e = expf(-fabsf(x));
        float r = 1.f / (1.f + e);
        float p = (x >= 0.f) ? r : 1.f - r;            // sigmoid(x), stable
        bce += fmaxf(x, 0.f) + log1pf(e) - x * (float)t;  // softplus - x*t
        vals[1 + b] = p;
        vals[9 + b] = t ? p : 0.f;
        vals[17 + b] = (float)t;
        sA += t ? 1.f - p : p;
    }
    sumA[pix] = sA;
    vals[0] = bce;
#pragma unroll
    for (int k = 0; k < 25; ++k)
#pragma unroll
        for (int o = 32; o; o >>= 1) vals[k] += __shfl_down(vals[k], o);
    __shared__ float lds[4][25];
    int wave = threadIdx.x >> 6, lane = threadIdx.x & 63;
    if (lane == 0)
#pragma unroll
        for (int k = 0; k < 25; ++k) lds[wave][k] = vals[k];
    __syncthreads();
    if (threadIdx.x < 25) {
        double s = (double)lds[0][threadIdx.x] + (double)lds[1][threadIdx.x]
                 + (double)lds[2][threadIdx.x] + (double)lds[3][threadIdx.x];
        part2[blockIdx.x * 25 + threadIdx.x] = s;
    }
}

// ---------------- kernel 2: vertical distance, word-parallel ----------------
// block = 64 columns x 12 words = 768 threads; thread = (word, col).
// Carry-in via nearest-set-bit search over other words; 32+32 int reg-scan.
__global__ __launch_bounds__(768) void k_vert(const int* __restrict__ tgt,
                                              unsigned* __restrict__ g2u) {
    __shared__ unsigned bmsh[12][64];
    int tid = threadIdx.x;
    int wd = tid >> 6;                 // 0..11  (== wave index)
    int wl = tid & 63;
    int b = blockIdx.x / 6;
    int w = (blockIdx.x % 6) * 64 + wl;

    const int* colp = tgt + b * HW + w + (wd * 32) * W;
    unsigned m = 0;
#pragma unroll
    for (int i = 0; i < 32; ++i)
        m |= (colp[i * W] != 0) ? (1u << i) : 0u;
    bmsh[wd][wl] = m;
    __syncthreads();

    unsigned mp = m, mn = ~m;

    int dfe_p = INF_I, dfe_n = INF_I, dbe_p = INF_I, dbe_n = INF_I;
    if (wd > 0) {
        int k = wd - 1; unsigned mm;
        while ((mm = bmsh[k][wl]) == 0 && k > 0) --k;
        if (mm) dfe_p = wd * 32 - 1 - (k * 32 + 31 - __clz(mm));
        k = wd - 1;
        while ((mm = ~bmsh[k][wl]) == 0 && k > 0) --k;
        if (mm) dfe_n = wd * 32 - 1 - (k * 32 + 31 - __clz(mm));
    }
    if (wd < 11) {
        int k = wd + 1; unsigned mm;
        while ((mm = bmsh[k][wl]) == 0 && k < 11) ++k;
        if (mm) dbe_p = k * 32 + (__ffs(mm) - 1) - (wd + 1) * 32;
        k = wd + 1;
        while ((mm = ~bmsh[k][wl]) == 0 && k < 11) ++k;
        if (mm) dbe_n = k * 32 + (__ffs(mm) - 1) - (wd + 1) * 32;
    }

    int dfp[32], dfn[32];
    int cp = dfe_p, cn = dfe_n;
#pragma unroll
    for (int i = 0; i < 32; ++i) {
        cp = ((mp >> i) & 1u) ? 0 : min(cp + 1, INF_I);
        cn = ((mn >> i) & 1u) ? 0 : min(cn + 1, INF_I);
        dfp[i] = cp; dfn[i] = cn;
    }
    unsigned* outc = g2u + b * HW + (wd * 32) * W + w;
    cp = dbe_p; cn = dbe_n;
#pragma unroll
    for (int i = 31; i >= 0; --i) {
        cp = ((mp >> i) & 1u) ? 0 : min(cp + 1, INF_I);
        cn = ((mn >> i) & 1u) ? 0 : min(cn + 1, INF_I);
        int dp = min(dfp[i], cp);
        int dn = min(dfn[i], cn);
        outc[i * W] = (unsigned)dp | ((unsigned)dn << 16);
    }
}

// ---------------- kernel 3: windowed row envelope + loss2 dot ----------------
// block = row (b,h), 64 thr, thread = 6 consecutive pixels. K=8 window with
// provable exactness check (D_win <= 64) + full-row fallback.
__global__ __launch_bounds__(64) void k_row(const unsigned* __restrict__ g2u,
                                            const float* __restrict__ sumA,
                                            double* __restrict__ part) {
    int bh = blockIdx.x;
    int b = bh / H, h = bh % H;
    __shared__ float lfp[W + W/16 + 2], lfn[W + W/16 + 2];   // +1 pad per 16
    const unsigned* row = g2u + b * HW + h * W;
    int tid = threadIdx.x;
    for (int q = tid; q < W; q += 64) {
        unsigned v = row[q];
        float dp = (float)(v & 0xFFFFu);
        float dn = (float)(v >> 16);
        int s = q + (q >> 4);
        lfp[s] = dp * dp;                 // exact: ints <= 1e4 -> d^2 <= 1e8
        lfn[s] = dn * dn;
    }
    __syncthreads();

    int base = 6 * tid - 8;
    float rp[22], rn[22];
#pragma unroll
    for (int r = 0; r < 22; ++r) {
        int j = base + r;
        j = j < 0 ? 0 : (j > W - 1 ? W - 1 : j);
        int s = j + (j >> 4);
        rp[r] = lfp[s];
        rn[r] = lfn[s];
    }
    const float DD[17] = {64.f,49.f,36.f,25.f,16.f,9.f,4.f,1.f,0.f,
                          1.f,4.f,9.f,16.f,25.f,36.f,49.f,64.f};
    float partial = 0.f;
#pragma unroll
    for (int q = 0; q < 6; ++q) {
        int i = 6 * tid + q;
        float Dp = 3.0e38f, Dn = 3.0e38f;
#pragma unroll
        for (int tt = 0; tt < 17; ++tt) {
            Dp = fminf(Dp, rp[q + tt] + DD[tt]);
            Dn = fminf(Dn, rn[q + tt] + DD[tt]);
        }
        if (Dp > 64.f || Dn > 64.f) {     // exactness not proven -> full row
            float fi = (float)i;
            for (int j = 0; j < W; ++j) {
                int s = j + (j >> 4);
                float d = fi - (float)j;
                Dp = fminf(Dp, fmaf(d, d, lfp[s]));
                Dn = fminf(Dn, fmaf(d, d, lfn[s]));
            }
        }
        float sdf = fabsf(sqrtf(Dp) - sqrtf(Dn));
        partial += sdf * sumA[h * W + i];
    }
    double v = partial;
#pragma unroll
    for (int o = 32; o; o >>= 1) v += __shfl_down(v, o);
    if (tid == 0) part[bh] = v;
}

// ---------------- kernel 4: final reduction + combine ----------------
__global__ __launch_bounds__(256) void k_final(const double* __restrict__ part2,
                                               const double* __restrict__ part,
                                               float* __restrict__ out) {
    __shared__ double sval[25];
    __shared__ double sl2[4];
    int tid = threadIdx.x;
    if (tid < 200) {
        int v = tid >> 3, sub = tid & 7;
        double s = 0.0;
        for (int blk = sub; blk < 576; blk += 8) s += part2[blk * 25 + v];
#pragma unroll
        for (int o = 4; o; o >>= 1) s += __shfl_down(s, o);
        if (sub == 0) sval[v] = s;
    }
    double s2 = 0.0;
    for (int i = tid; i < B * H; i += 256) s2 += part[i];
#pragma unroll
    for (int o = 32; o; o >>= 1) s2 += __shfl_down(s2, o);
    if ((tid & 63) == 0) sl2[tid >> 6] = s2;
    __syncthreads();
    if (tid == 0) {
        double bce = sval[0] / (double)NTOT;
        double dsum = 0.0;
        for (int b = 0; b < 8; ++b)
            dsum += (2.0 * sval[9 + b] + 1e-5) / (sval[1 + b] + sval[17 + b] + 1e-5);
        double dice = dsum / 8.0;
        double loss1 = 0.5 * bce + (1.0 - dice);
        double loss2 = (sl2[0] + sl2[1] + sl2[2] + sl2[3])
                     / ((double)B * (double)B * (double)HW);
        out[0] = (float)(0.7 * loss1 + 0.03 * loss2);
    }
}

extern "C" void kernel_launch(void* const* d_in, const int* in_sizes, int n_in,
                              void* d_out, int out_size, void* d_ws, size_t ws_size,
                              hipStream_t stream) {
    const float* pred = (const float*)d_in[0];
    const int* tgt = (const int*)d_in[1];
    float* out = (float*)d_out;
    char* ws = (char*)d_ws;
    double* part2 = (double*)ws;
    double* part = (double*)(ws + 115200);
    unsigned* g2u = (unsigned*)(ws + 139776);
    float* sumA = (float*)(ws + 4858368);

    k_fused<<<NTOT / (8 * 256), 256, 0, stream>>>(pred, tgt, sumA, part2);
    k_vert<<<B * 6, 768, 0, stream>>>(tgt, g2u);
    k_row<<<B * H, 64, 0, stream>>>(g2u, sumA, part);
    k_final<<<1, 256, 0, stream>>>(part2, part, out);
}